// Round 1
// baseline (85.005 us; speedup 1.0000x reference)
//
#include <hip/hip_runtime.h>

#define NHEADS 8
#define NN     128           // nodes per graph
#define NCELL  (NN * NN)     // 16384 floats = 64 KiB
#define SCALE_F 10.0f

// Layout notes
// ------------
// One block (512 threads) per graph. Thread t owns rows r=t>>3 and r+64,
// columns [jb*16, jb*16+16) where jb=t&7 -> 32 register-resident cells.
//
// LDS (exactly 64 KiB) is time-multiplexed:
//   init/scatter/load + final writeback : full 128x128 matrix, XOR-swizzled:
//        element (i, col) at  lds[i*128 + (col ^ ((i&7)<<2))]
//   during FW (matrix dead, regs hold truth):
//        rowbuf[b] = lds[b*192 .. +192)   8 groups of 24 floats (16 payload + 8 pad)
//        colbuf[b] = lds[384 + b*128 ..)
//        red       = lds[640 .. 656)

__global__ __launch_bounds__(512)
void spb_fw_kernel(const int* __restrict__ edge_index,
                   const float* __restrict__ edge_weight,
                   const int num_edges, const int epg,
                   float* __restrict__ out)
{
    __shared__ float lds[NCELL];
    const float INF = __builtin_huge_valf();
    const int t  = threadIdx.x;
    const int g  = blockIdx.x;
    const int jb = t & 7;          // column group (16 cols each)
    const int r  = t >> 3;         // 0..63 ; owns rows r and r+64
    const int colbase = jb << 4;

    // ---- Phase 1: init dist matrix (linear writes into swizzled storage) ----
    #pragma unroll
    for (int c = 0; c < 8; ++c) {
        const int m   = t + (c << 9);          // float4 chunk index (storage space)
        const int i   = m >> 5;
        const int scm = m & 31;
        const int c0  = (scm ^ (i & 7)) << 2;  // logical col base of this chunk
        float4 v;
        v.x = (c0 + 0 == i) ? 0.0f : INF;
        v.y = (c0 + 1 == i) ? 0.0f : INF;
        v.z = (c0 + 2 == i) ? 0.0f : INF;
        v.w = (c0 + 3 == i) ? 0.0f : INF;
        *reinterpret_cast<float4*>(&lds[m << 2]) = v;
    }
    __syncthreads();

    // ---- Phase 2: scatter edges (min).  positive floats: int order == float order ----
    const int ebase = g * epg;
    for (int e = t; e < epg; e += 512) {
        const int idx = ebase + e;
        const int src = edge_index[idx];
        const int dst = edge_index[num_edges + idx];
        const float w = edge_weight[idx];
        const int u = src - g * NN;
        const int v = dst - g * NN;
        if (u != v && (unsigned)u < (unsigned)NN && (unsigned)v < (unsigned)NN) {
            const int a = (u << 7) + (v ^ ((u & 7) << 2));
            atomicMin(reinterpret_cast<int*>(&lds[a]), __float_as_int(w));
        }
    }
    __syncthreads();

    // ---- Phase 3: load 32 cells into registers ----
    float dA[16], dB[16];
    {
        const int sA = (r & 7) << 2;           // same swizzle for r and r+64
        #pragma unroll
        for (int c = 0; c < 4; ++c) {
            const int cc = (colbase + (c << 2)) ^ sA;
            float4 a = *reinterpret_cast<const float4*>(&lds[(r << 7) + cc]);
            float4 b = *reinterpret_cast<const float4*>(&lds[((r + 64) << 7) + cc]);
            dA[c*4+0] = a.x; dA[c*4+1] = a.y; dA[c*4+2] = a.z; dA[c*4+3] = a.w;
            dB[c*4+0] = b.x; dB[c*4+1] = b.y; dB[c*4+2] = b.z; dB[c*4+3] = b.w;
        }
    }
    __syncthreads();   // all matrix reads done; buf region may now be clobbered

    // seed row-0 / col-0 buffers (k = 0) from registers
    if (r == 0) {
        #pragma unroll
        for (int c = 0; c < 4; ++c) {
            float4 v = make_float4(dA[c*4], dA[c*4+1], dA[c*4+2], dA[c*4+3]);
            *reinterpret_cast<float4*>(&lds[jb * 24 + (c << 2)]) = v;
        }
    }
    if (jb == 0) {
        lds[384 + r]      = dA[0];
        lds[384 + r + 64] = dB[0];
    }

    // ---- Phase 4: Floyd-Warshall, double-buffered row/col, 1 barrier/iter ----
    for (int ko = 0; ko < 8; ++ko) {
        #pragma unroll
        for (int kk = 0; kk < 16; ++kk) {
            const int k   = (ko << 4) + kk;
            const int cur = kk & 1;
            const int nxt = cur ^ 1;
            float* rb  = &lds[cur * 192];
            float* cb  = &lds[384 + (cur << 7)];
            float* rbn = &lds[nxt * 192];
            float* cbn = &lds[384 + (nxt << 7)];
            __syncthreads();
            const float cA = cb[r];
            const float cB = cb[r + 64];
            float rk[16];
            #pragma unroll
            for (int c = 0; c < 4; ++c) {
                float4 v = *reinterpret_cast<const float4*>(&rb[jb * 24 + (c << 2)]);
                rk[c*4+0] = v.x; rk[c*4+1] = v.y; rk[c*4+2] = v.z; rk[c*4+3] = v.w;
            }
            #pragma unroll
            for (int j = 0; j < 16; ++j) {
                dA[j] = fminf(dA[j], cA + rk[j]);
                dB[j] = fminf(dB[j], cB + rk[j]);
            }
            // publish row/col (k+1); guards vanish naturally at kn==128
            const int kn = k + 1;
            if ((kn >> 4) == jb) {              // column owner
                cbn[r]      = dA[(kk + 1) & 15];  // compile-time reg index
                cbn[r + 64] = dB[(kk + 1) & 15];
            }
            if (r == kn) {                      // row owner (kn < 64)
                #pragma unroll
                for (int c = 0; c < 4; ++c) {
                    float4 v = make_float4(dA[c*4], dA[c*4+1], dA[c*4+2], dA[c*4+3]);
                    *reinterpret_cast<float4*>(&rbn[jb * 24 + (c << 2)]) = v;
                }
            } else if (r + 64 == kn) {          // row owner (64 <= kn < 128)
                #pragma unroll
                for (int c = 0; c < 4; ++c) {
                    float4 v = make_float4(dB[c*4], dB[c*4+1], dB[c*4+2], dB[c*4+3]);
                    *reinterpret_cast<float4*>(&rbn[jb * 24 + (c << 2)]) = v;
                }
            }
        }
    }
    __syncthreads();

    // ---- Phase 5: per-graph reductions (max finite, global max) ----
    float mF = 0.0f, mA = 0.0f;   // diag==0 guarantees a finite value exists
    #pragma unroll
    for (int j = 0; j < 16; ++j) {
        mA = fmaxf(mA, fmaxf(dA[j], dB[j]));
        mF = fmaxf(mF, fmaxf(dA[j] < INF ? dA[j] : 0.0f,
                             dB[j] < INF ? dB[j] : 0.0f));
    }
    #pragma unroll
    for (int o = 32; o > 0; o >>= 1) {
        mF = fmaxf(mF, __shfl_xor(mF, o));
        mA = fmaxf(mA, __shfl_xor(mA, o));
    }
    if ((t & 63) == 0) {
        lds[640 + ((t >> 6) << 1)]     = mF;
        lds[640 + ((t >> 6) << 1) + 1] = mA;
    }
    __syncthreads();
    mF = lds[640]; mA = lds[641];
    #pragma unroll
    for (int wv = 1; wv < 8; ++wv) {
        mF = fmaxf(mF, lds[640 + wv * 2]);
        mA = fmaxf(mA, lds[640 + wv * 2 + 1]);
    }
    const float twoF  = 2.0f * mF;
    const float maxv  = fmaxf((mA == INF) ? twoF : mF, 1e-8f);
    const float nscal = -SCALE_F / maxv;
    __syncthreads();   // protect red reads before writeback clobbers lds[640..]

    // ---- Phase 6: bias write-back to LDS (swizzled) ----
    {
        const int sA = (r & 7) << 2;
        #pragma unroll
        for (int c = 0; c < 4; ++c) {
            const int cc = (colbase + (c << 2)) ^ sA;
            float4 va, vb;
            va.x = ((dA[c*4+0] == INF) ? twoF : dA[c*4+0]) * nscal;
            va.y = ((dA[c*4+1] == INF) ? twoF : dA[c*4+1]) * nscal;
            va.z = ((dA[c*4+2] == INF) ? twoF : dA[c*4+2]) * nscal;
            va.w = ((dA[c*4+3] == INF) ? twoF : dA[c*4+3]) * nscal;
            vb.x = ((dB[c*4+0] == INF) ? twoF : dB[c*4+0]) * nscal;
            vb.y = ((dB[c*4+1] == INF) ? twoF : dB[c*4+1]) * nscal;
            vb.z = ((dB[c*4+2] == INF) ? twoF : dB[c*4+2]) * nscal;
            vb.w = ((dB[c*4+3] == INF) ? twoF : dB[c*4+3]) * nscal;
            *reinterpret_cast<float4*>(&lds[(r << 7) + cc]) = va;
            *reinterpret_cast<float4*>(&lds[((r + 64) << 7) + cc]) = vb;
        }
    }
    __syncthreads();

    // ---- Phase 7: replicate to 8 heads, coalesced stores (un-swizzle chunk idx) ----
    float* const outg = out + (size_t)g * (NHEADS * NCELL);
    #pragma unroll
    for (int c = 0; c < 8; ++c) {
        const int m   = t + (c << 9);
        const int i   = m >> 5;
        const int scm = m & 31;
        const int lm  = (i << 5) + (scm ^ (i & 7));   // logical chunk index
        const float4 v = *reinterpret_cast<const float4*>(&lds[m << 2]);
        #pragma unroll
        for (int h = 0; h < NHEADS; ++h) {
            *reinterpret_cast<float4*>(&outg[(size_t)h * NCELL + (lm << 2)]) = v;
        }
    }
}

extern "C" void kernel_launch(void* const* d_in, const int* in_sizes, int n_in,
                              void* d_out, int out_size, void* d_ws, size_t ws_size,
                              hipStream_t stream)
{
    const int*   edge_index  = (const int*)d_in[0];
    const float* edge_w      = (const float*)d_in[1];
    const int E    = in_sizes[1];          // 524288
    const int Ntot = in_sizes[2];          // 32768
    const int G    = Ntot / NN;            // 256 graphs
    const int epg  = E / G;                // 2048 edges/graph (contiguous blocks)
    float* out = (float*)d_out;
    spb_fw_kernel<<<G, 512, 0, stream>>>(edge_index, edge_w, E, epg, out);
}